// Round 4
// baseline (106.120 us; speedup 1.0000x reference)
//
#include <hip/hip_runtime.h>
#include <hip/hip_cooperative_groups.h>
#include <math.h>

namespace cg = cooperative_groups;

// Problem constants (fixed by setup_inputs: B=64, HW=6400 (80x80), C=85, T=50)
constexpr int B_  = 64;
constexpr int HW_ = 6400;
constexpr int C_  = 85;
constexpr int T_  = 50;
constexpr int H_  = 80;
constexpr int W_  = 80;
constexpr float LC    = 5.0f;              // LAMBDA_COORD
constexpr float LN    = 0.5f;              // LAMBDA_NOOBJ
constexpr float INV_N = 1.0f / (B_ * T_);  // 1/num_objects

constexpr int GRID       = 1024;           // 4 blocks/CU on 256 CUs (co-resident)
constexpr int OBJ_BLOCKS = (B_ * T_) / 4;  // 800 blocks carry 4 obj-waves each
constexpr int SUBN       = 16;             // conf sub-blocks per image (64*16=1024)
constexpr int CHUNK      = HW_ / SUBN;     // 400 cells per block

// ws layout (floats) — every word written each call before read: no memsets.
constexpr int OFF_PEROBJ = 0;                    // [3200] per-object loss
constexpr int OFF_MSP    = OFF_PEROBJ + B_ * T_; // [3200] softplus(conf) if canonical
constexpr int OFF_CANON  = OFF_MSP + B_ * T_;    // [3200] 1.0 if canonical
constexpr int OFF_PART   = OFF_CANON + B_ * T_;  // [1024] per-(image,sub) conf sums

__device__ __forceinline__ float softplus_f(float x) {
    return fmaxf(x, 0.0f) + log1pf(expf(-fabsf(x)));   // stable log(1+e^x)
}

__global__ __launch_bounds__(256) void fused_kernel(
    const float* __restrict__ pred, const float* __restrict__ tbox,
    const int* __restrict__ tcls,
    float* __restrict__ per_obj, float* __restrict__ masked_sp,
    float* __restrict__ canon, float* __restrict__ img_part,
    float* __restrict__ out)
{
    cg::grid_group grid = cg::this_grid();
    __shared__ float ss[4];
    __shared__ float simg[B_];

    // ---- phase 1a: per-object waves (blocks 0..799, 4 objects/block) ----
    if (blockIdx.x < OBJ_BLOCKS) {
        int obj  = blockIdx.x * 4 + (threadIdx.x >> 6);
        int lane = threadIdx.x & 63;
        int b    = obj / T_;
        int myt  = obj % T_;

        const float4 tb = ((const float4*)tbox)[obj];   // cx, cy, w, h
        float gxf = floorf(tb.x * (float)W_);
        float gyf = floorf(tb.y * (float)H_);
        int gi = (int)(gyf * (float)W_ + gxf);

        // canonical = no earlier object in this image occupies the same cell
        bool dup = false;
        if (lane < T_) {
            const float4 to = ((const float4*)tbox)[b * T_ + lane];
            int gio = (int)(floorf(to.y * (float)H_) * (float)W_ +
                            floorf(to.x * (float)W_));
            dup = (lane < myt) && (gio == gi);
        }
        bool canonical = (__ballot(dup) == 0ULL);

        const float* g = pred + ((size_t)b * HW_ + gi) * C_;
        int cls = tcls[obj];

        int   c2 = lane + 64;
        float v1 = g[lane];
        float v2 = (c2 < C_) ? g[c2] : 0.0f;

        // logsumexp over class channels 5..84
        float m = -1e30f;
        if (lane >= 5) m = v1;
        if (c2 < C_)   m = fmaxf(m, v2);
        #pragma unroll
        for (int off = 32; off; off >>= 1) m = fmaxf(m, __shfl_xor(m, off, 64));
        float s = 0.0f;
        if (lane >= 5) s += expf(v1 - m);
        if (c2 < C_)   s += expf(v2 - m);
        #pragma unroll
        for (int off = 32; off; off >>= 1) s += __shfl_xor(s, off, 64);
        float lse = m + logf(s);

        float contrib = 0.0f;
        if (lane == 0) {          // xy: mean over 2 comps -> 0.5 each, * LC
            float d = 1.0f / (1.0f + expf(-v1)) - (tb.x * (float)W_ - gxf);
            contrib = LC * 0.5f * d * d;
        } else if (lane == 1) {
            float d = 1.0f / (1.0f + expf(-v1)) - (tb.y * (float)H_ - gyf);
            contrib = LC * 0.5f * d * d;
        } else if (lane == 2) {
            float d = v1 - logf(tb.z * (float)W_ + 1e-16f);
            contrib = LC * 0.5f * d * d;
        } else if (lane == 3) {
            float d = v1 - logf(tb.w * (float)H_ + 1e-16f);
            contrib = LC * 0.5f * d * d;
        } else if (lane == 4) {
            contrib = softplus_f(-v1);                   // objectness BCE
            masked_sp[obj] = canonical ? softplus_f(v1) : 0.0f;
        }
        if (lane == 5 + cls) contrib += lse - v1;        // class CE
        if (c2   == 5 + cls) contrib += lse - v2;

        #pragma unroll
        for (int off = 32; off; off >>= 1) contrib += __shfl_xor(contrib, off, 64);
        if (lane == 0) {
            per_obj[obj] = contrib;
            canon[obj]   = canonical ? 1.0f : 0.0f;
        }
    }

    // ---- phase 1b: conf softplus scan (all 1024 blocks, 400 cells each) ----
    {
        int c    = blockIdx.x;
        int b    = c >> 4;          // image
        int sub  = c & 15;
        int base = sub * CHUNK;
        const float* p = pred + (size_t)b * HW_ * C_;

        float sum = 0.0f;
        for (int i = base + (int)threadIdx.x; i < base + CHUNK; i += 256)
            sum += softplus_f(p[(size_t)i * C_ + 4]);
        #pragma unroll
        for (int off = 32; off; off >>= 1) sum += __shfl_xor(sum, off, 64);

        int wid = threadIdx.x >> 6;
        if ((threadIdx.x & 63) == 0) ss[wid] = sum;
        __syncthreads();
        if (threadIdx.x == 0)
            img_part[c] = ss[0] + ss[1] + ss[2] + ss[3];
    }

    grid.sync();

    // ---- phase 2: combine (block 0 only) ----
    if (blockIdx.x == 0) {
        int t = threadIdx.x;
        int b = t >> 2;      // image
        int q = t & 3;       // quarter

        float po = 0.0f, msp = 0.0f, cn = 0.0f, tp = 0.0f;
        for (int i = q; i < T_; i += 4) {
            po  += per_obj[b * T_ + i];
            msp += masked_sp[b * T_ + i];
            cn  += canon[b * T_ + i];
        }
        for (int j = q; j < SUBN; j += 4)
            tp += img_part[b * SUBN + j];

        #pragma unroll
        for (int off = 1; off <= 2; off <<= 1) {
            po  += __shfl_xor(po,  off, 64);
            msp += __shfl_xor(msp, off, 64);
            cn  += __shfl_xor(cn,  off, 64);
            tp  += __shfl_xor(tp,  off, 64);
        }

        if (q == 0) {
            float n_noobj = fmaxf((float)HW_ - cn, 1.0f);
            simg[b] = po + LN * (tp - msp) / n_noobj;
        }
        __syncthreads();

        if (t < 64) {
            float v = simg[t];
            #pragma unroll
            for (int off = 32; off; off >>= 1) v += __shfl_xor(v, off, 64);
            if (t == 0) out[0] = v * INV_N;
        }
    }
}

extern "C" void kernel_launch(void* const* d_in, const int* in_sizes, int n_in,
                              void* d_out, int out_size, void* d_ws, size_t ws_size,
                              hipStream_t stream) {
    const float* pred = (const float*)d_in[0];
    const float* tbox = (const float*)d_in[1];
    const int*   tcls = (const int*)d_in[2];
    float* out = (float*)d_out;

    float* ws        = (float*)d_ws;
    float* per_obj   = ws + OFF_PEROBJ;
    float* masked_sp = ws + OFF_MSP;
    float* canon     = ws + OFF_CANON;
    float* img_part  = ws + OFF_PART;

    void* args[] = {
        (void*)&pred, (void*)&tbox, (void*)&tcls,
        (void*)&per_obj, (void*)&masked_sp, (void*)&canon,
        (void*)&img_part, (void*)&out
    };
    hipLaunchCooperativeKernel((const void*)fused_kernel,
                               dim3(GRID), dim3(256), args, 0, stream);
}

// Round 5
// 20.817 us; speedup vs baseline: 5.0977x; 5.0977x over previous
//
#include <hip/hip_runtime.h>
#include <math.h>

// Problem constants (fixed by setup_inputs: B=64, HW=6400 (80x80), C=85, T=50)
constexpr int B_  = 64;
constexpr int HW_ = 6400;
constexpr int C_  = 85;
constexpr int T_  = 50;
constexpr int H_  = 80;
constexpr int W_  = 80;
constexpr float LC    = 5.0f;              // LAMBDA_COORD
constexpr float LN    = 0.5f;              // LAMBDA_NOOBJ
constexpr float INV_N = 1.0f / (B_ * T_);  // 1/num_objects

constexpr int CHUNKS_PER_IMG = 25;                    // 25 * 256 = 6400 cells
constexpr int SCAN_BLOCKS    = B_ * CHUNKS_PER_IMG;   // 1600
constexpr int OBJ_BLOCKS     = (B_ * T_) / 4;         // 800 (4 obj-waves each)
constexpr int GRID_A         = SCAN_BLOCKS + OBJ_BLOCKS; // 2400
constexpr int NPART          = SCAN_BLOCKS + B_ * T_; // 1600 + 3200 = 4800 floats

__device__ __forceinline__ float softplus_f(float x) {
    return fmaxf(x, 0.0f) + log1pf(expf(-fabsf(x)));   // stable log(1+e^x)
}

// Per-wave: lane<50 holds grid-index of object `lane` of image b; returns the
// duplicate mask (bit l set = object l has an earlier object in the same cell).
__device__ __forceinline__ unsigned long long dup_mask_for_image(
    const float* __restrict__ tbox, int b, int lane)
{
    int gio;
    if (lane < T_) {
        const float4 to = ((const float4*)tbox)[b * T_ + lane];
        gio = (int)(floorf(to.y * (float)H_) * (float)W_ +
                    floorf(to.x * (float)W_));
    } else {
        gio = 0x40000000 + lane;   // unique sentinel, never matches
    }
    bool dup = false;
    #pragma unroll
    for (int k = 0; k < T_ - 1; ++k) {
        int gk = __shfl(gio, k, 64);
        dup = dup || ((lane > k) && (gio == gk));
    }
    return __ballot(dup);
}

// Kernel A: blocks [0,1600) scan 256 conf cells each (1 load/thread);
//           blocks [1600,2400) run 4 object-waves each.
// Every emitted partial is already scaled so the final answer is just a sum.
__global__ __launch_bounds__(256) void main_kernel(
    const float* __restrict__ pred, const float* __restrict__ tbox,
    const int* __restrict__ tcls, float* __restrict__ partial)
{
    int lane = threadIdx.x & 63;
    int wid  = threadIdx.x >> 6;
    __shared__ float ss[4];

    if (blockIdx.x < SCAN_BLOCKS) {
        // ---- conf softplus scan; emit LN * (chunk sum) / nn_b ----
        int c   = blockIdx.x;
        int b   = c / CHUNKS_PER_IMG;
        int sub = c % CHUNKS_PER_IMG;

        unsigned long long dm = dup_mask_for_image(tbox, b, lane);
        int n_unique = T_ - __popcll(dm);
        float nn = fmaxf((float)(HW_ - n_unique), 1.0f);

        int cell = sub * 256 + (int)threadIdx.x;
        float conf = pred[((size_t)b * HW_ + cell) * C_ + 4];
        float s = softplus_f(conf);
        #pragma unroll
        for (int off = 32; off; off >>= 1) s += __shfl_xor(s, off, 64);
        if (lane == 0) ss[wid] = s;
        __syncthreads();
        if (threadIdx.x == 0)
            partial[c] = LN * (ss[0] + ss[1] + ss[2] + ss[3]) / nn;
    } else {
        // ---- per-object wave; emit per_obj - canonical*LN*softplus(conf)/nn ----
        int obj = (blockIdx.x - SCAN_BLOCKS) * 4 + wid;
        int b   = obj / T_;
        int myt = obj % T_;

        const float4 tb = ((const float4*)tbox)[obj];   // cx, cy, w, h
        float gxf = floorf(tb.x * (float)W_);
        float gyf = floorf(tb.y * (float)H_);
        int gi = (int)(gyf * (float)W_ + gxf);

        unsigned long long dm = dup_mask_for_image(tbox, b, lane);
        bool canonical = !((dm >> myt) & 1ULL);
        int n_unique = T_ - __popcll(dm);
        float nn = fmaxf((float)(HW_ - n_unique), 1.0f);

        const float* g = pred + ((size_t)b * HW_ + gi) * C_;
        int cls = tcls[obj];

        int   c2 = lane + 64;
        float v1 = g[lane];
        float v2 = (c2 < C_) ? g[c2] : 0.0f;

        // logsumexp over class channels 5..84
        float m = -1e30f;
        if (lane >= 5) m = v1;
        if (c2 < C_)   m = fmaxf(m, v2);
        #pragma unroll
        for (int off = 32; off; off >>= 1) m = fmaxf(m, __shfl_xor(m, off, 64));
        float s = 0.0f;
        if (lane >= 5) s += expf(v1 - m);
        if (c2 < C_)   s += expf(v2 - m);
        #pragma unroll
        for (int off = 32; off; off >>= 1) s += __shfl_xor(s, off, 64);
        float lse = m + logf(s);

        float contrib = 0.0f;
        if (lane == 0) {          // xy: mean over 2 comps -> 0.5 each, * LC
            float d = 1.0f / (1.0f + expf(-v1)) - (tb.x * (float)W_ - gxf);
            contrib = LC * 0.5f * d * d;
        } else if (lane == 1) {
            float d = 1.0f / (1.0f + expf(-v1)) - (tb.y * (float)H_ - gyf);
            contrib = LC * 0.5f * d * d;
        } else if (lane == 2) {
            float d = v1 - logf(tb.z * (float)W_ + 1e-16f);
            contrib = LC * 0.5f * d * d;
        } else if (lane == 3) {
            float d = v1 - logf(tb.w * (float)H_ + 1e-16f);
            contrib = LC * 0.5f * d * d;
        } else if (lane == 4) {
            contrib = softplus_f(-v1);                   // objectness BCE
            if (canonical) contrib -= LN * softplus_f(v1) / nn;  // -masked noobj part
        }
        if (lane == 5 + cls) contrib += lse - v1;        // class CE
        if (c2   == 5 + cls) contrib += lse - v2;

        #pragma unroll
        for (int off = 32; off; off >>= 1) contrib += __shfl_xor(contrib, off, 64);
        if (lane == 0) partial[SCAN_BLOCKS + obj] = contrib;
    }
}

// Kernel B: one block sums the 4800 partials (1200 float4, coalesced) -> out.
__global__ __launch_bounds__(256) void reduce_kernel(
    const float* __restrict__ partial, float* __restrict__ out)
{
    const float4* p4 = (const float4*)partial;   // 4800/4 = 1200
    float s = 0.0f;
    for (int i = threadIdx.x; i < NPART / 4; i += 256) {
        float4 v = p4[i];
        s += (v.x + v.y) + (v.z + v.w);
    }
    #pragma unroll
    for (int off = 32; off; off >>= 1) s += __shfl_xor(s, off, 64);

    __shared__ float ss[4];
    int wid = threadIdx.x >> 6;
    if ((threadIdx.x & 63) == 0) ss[wid] = s;
    __syncthreads();
    if (threadIdx.x == 0)
        out[0] = (ss[0] + ss[1] + ss[2] + ss[3]) * INV_N;
}

extern "C" void kernel_launch(void* const* d_in, const int* in_sizes, int n_in,
                              void* d_out, int out_size, void* d_ws, size_t ws_size,
                              hipStream_t stream) {
    const float* pred = (const float*)d_in[0];
    const float* tbox = (const float*)d_in[1];
    const int*   tcls = (const int*)d_in[2];
    float* out = (float*)d_out;
    float* partial = (float*)d_ws;   // [4800], fully written before read

    main_kernel<<<GRID_A, 256, 0, stream>>>(pred, tbox, tcls, partial);
    reduce_kernel<<<1, 256, 0, stream>>>(partial, out);
}